// Round 1
// baseline (35316.541 us; speedup 1.0000x reference)
//
#include <hip/hip_runtime.h>

// SNN-MNIST forward + STDP, MI355X persistent cooperative kernel.
// T=200 sequential steps, 2 grid barriers per step.
// State lives in d_ws (zeroed via hipMemsetAsync each launch).

#define T_STEPS 200
#define BATCH   256
#define INQ     784
#define NOUT    400
#define NP      512            // padded stride for N-dim arrays
#define GRID    256
#define NTHR    256

// ws layout (float offsets)
#define OFF_WT    0            // Wt  [784][512]  (W transposed, padded)
#define OFF_SYN   401408       // syn [256][512]
#define OFF_MEM   532480       // mem [256][512]
#define OFF_SPPO  663552       // interleaved (spk,post): [256][1024] = (s_n,p_n,s_n+1,p_n+1)...
#define OFF_TRA   925696       // trA [256][784]
#define OFF_TRB   1126400      // trB [256][784]
#define OFF_WIN   1327104      // int win[256]
#define OFF_FLAGS 1327360      // int flags[256] (per-step any-spike)
#define OFF_BAR   1327616      // unsigned bar[8]: [0]=cnt [1]=gen
#define WS_FLOATS 1327624

__device__ __forceinline__ void gbar(unsigned* bar) {
  __threadfence();                 // release: make this block's writes device-visible
  __syncthreads();
  if (threadIdx.x == 0) {
    unsigned* cnt = bar;
    unsigned* gen = bar + 1;
    unsigned g = __hip_atomic_load(gen, __ATOMIC_RELAXED, __HIP_MEMORY_SCOPE_AGENT);
    unsigned a = __hip_atomic_fetch_add(cnt, 1u, __ATOMIC_ACQ_REL, __HIP_MEMORY_SCOPE_AGENT);
    if (a == GRID - 1u) {
      __hip_atomic_store(cnt, 0u, __ATOMIC_RELAXED, __HIP_MEMORY_SCOPE_AGENT);
      __hip_atomic_store(gen, g + 1u, __ATOMIC_RELEASE, __HIP_MEMORY_SCOPE_AGENT);
    } else {
      while (__hip_atomic_load(gen, __ATOMIC_RELAXED, __HIP_MEMORY_SCOPE_AGENT) == g) {
        __builtin_amdgcn_s_sleep(2);
      }
    }
  }
  __syncthreads();
  __threadfence();                 // acquire: invalidate stale cached lines
}

__global__ void __launch_bounds__(NTHR) snn_kernel(
    const float* __restrict__ img,   // [200][256][784]
    const float* __restrict__ Win,   // [400][784]
    float* __restrict__ out,         // mem_rec | spk_rec | W_final
    float* ws)
{
  float* Wt    = ws + OFF_WT;
  float* syn   = ws + OFF_SYN;
  float* mem   = ws + OFF_MEM;
  float* sppo  = ws + OFF_SPPO;
  float* trA   = ws + OFF_TRA;
  float* trB   = ws + OFF_TRB;
  int*   win   = (int*)(ws + OFF_WIN);
  int*   flags = (int*)(ws + OFF_FLAGS);
  unsigned* bar = (unsigned*)(ws + OFF_BAR);

  float* mem_rec = out;
  float* spk_rec = out + (size_t)T_STEPS * BATCH * NOUT;      // +20480000
  float* Wout    = out + (size_t)2 * T_STEPS * BATCH * NOUT;  // +40960000

  const int tid = threadIdx.x;
  const int blk = blockIdx.x;

  __shared__ int s_list[800];
  __shared__ int s_cnt;
  __shared__ int s_red[NTHR];

  // ---- init: Wt[i][n] = Win[n][i] (ws was memset to 0 on the stream) ----
  for (int e = blk * NTHR + tid; e < NOUT * INQ; e += GRID * NTHR) {
    int n = e / INQ, i = e % INQ;
    Wt[(size_t)i * NP + n] = Win[e];
  }
  gbar(bar);

  for (int t = 0; t < T_STEPS; ++t) {
    float* trC = (t & 1) ? trB : trA;   // pre_traces[t]
    float* trN = (t & 1) ? trA : trB;   // will hold pre_traces[t+1]

    // ================= phase 1: block b = batch row =================
    {
      const int b = blk;
      const float* imrow = img + ((size_t)t * BATCH + b) * INQ;
      float* trCrow = trC + (size_t)b * INQ;
      float* trNrow = trN + (size_t)b * INQ;
      // trace recurrence: tr_{t+1} = 0.9*tr_t + img_t
      for (int i = tid; i < INQ; i += NTHR) {
        float v = imrow[i];
        trNrow[i] = fmaf(0.9f, trCrow[i], v);
      }
      // ordered active-index compaction (wave 0)
      if (tid < 64) {
        int base = 0;
        for (int c = 0; c < INQ; c += 64) {
          int i = c + tid;
          bool act = (i < INQ) && (imrow[i] != 0.0f);
          unsigned long long m = __ballot(act);
          if (act) {
            int pos = (int)__popcll(m & ((1ull << tid) - 1ull));
            s_list[base + pos] = i;
          }
          base += (int)__popcll(m);
        }
        if (tid == 0) s_cnt = base;
      }
      __syncthreads();
      const int cnt = s_cnt;
      const int anyPrev = (t > 0) ? flags[t - 1] : 0;
      const int wPrev = win[b];         // valid when anyPrev
      int localmin = 0x7fffffff;

      if (tid < 200) {                  // thread handles n = 2*tid, 2*tid+1
        const int n0 = tid * 2;
        const size_t sidx = (size_t)b * NP + n0;
        float2 sv = *(float2*)(syn + sidx);
        if (anyPrev) {                  // deferred lateral inhibition from step t-1
          if (n0     != wPrev) sv.x -= 0.1f;
          if (n0 + 1 != wPrev) sv.y -= 0.1f;
        }
        float c0 = 0.f, c1 = 0.f;       // cur = sparse gather-sum of W rows
        for (int j = 0; j < cnt; ++j) {
          const float2 w2 = *(const float2*)(Wt + (size_t)s_list[j] * NP + n0);
          c0 += w2.x; c1 += w2.y;
        }
        float2 mv = *(float2*)(mem + sidx);
        float syn0 = fmaf(0.9f, sv.x, c0);
        float syn1 = fmaf(0.9f, sv.y, c1);
        float r0 = (mv.x > 1.0f) ? 1.0f : 0.0f;   // reset from incoming mem
        float r1 = (mv.y > 1.0f) ? 1.0f : 0.0f;
        float m0 = fmaf(0.8f, mv.x, syn0) - r0;
        float m1 = fmaf(0.8f, mv.y, syn1) - r1;
        float s0 = (m0 > 1.0f) ? 1.0f : 0.0f;
        float s1 = (m1 > 1.0f) ? 1.0f : 0.0f;
        *(float2*)(syn + sidx) = make_float2(syn0, syn1);
        *(float2*)(mem + sidx) = make_float2(m0, m1);
        // post trace (STDP uses updated post); interleaved store for phase 2
        float4 sp = *(float4*)(sppo + (size_t)b * 2 * NP + 2 * n0);
        float p0 = fmaf(0.9f, sp.y, s0);
        float p1 = fmaf(0.9f, sp.w, s1);
        *(float4*)(sppo + (size_t)b * 2 * NP + 2 * n0) = make_float4(s0, p0, s1, p1);
        const size_t ridx = (size_t)t * BATCH * NOUT + (size_t)b * NOUT + n0;
        *(float2*)(mem_rec + ridx) = make_float2(m0, m1);
        *(float2*)(spk_rec + ridx) = make_float2(s0, s1);
        if      (s0 != 0.f) localmin = n0;
        else if (s1 != 0.f) localmin = n0 + 1;
      }
      // win[b] = first spiking n (argmax semantics), 0 if none
      s_red[tid] = localmin;
      __syncthreads();
      for (int o = NTHR / 2; o > 0; o >>= 1) {
        if (tid < o) s_red[tid] = min(s_red[tid], s_red[tid + o]);
        __syncthreads();
      }
      if (tid == 0) {
        int w = s_red[0];
        win[b] = (w == 0x7fffffff) ? 0 : w;
        if (w != 0x7fffffff) atomicOr(&flags[t], 1);
      }
    }
    gbar(bar);

    // ================= phase 2: STDP weight update =================
    // Wt[i][n] = clip(Wt + sum_b(1e-3*spk*tr - 1e-3*post*img)), 13x13 blocks,
    // 64i x 32n tiles, 4i x 2n per thread, operands streamed from L2.
    if (blk < 169) {
      const int bi = blk / 13, bn = blk % 13;
      const int ib = bi * 64 + (tid >> 4) * 4;
      const int nb = bn * 32 + (tid & 15) * 2;
      if (ib < INQ && nb < NOUT) {
        float a00=0,a01=0,a10=0,a11=0,a20=0,a21=0,a30=0,a31=0;
        const float* trp = trC + ib;
        const float* imp = img + (size_t)t * BATCH * INQ + ib;
        const float* spp = sppo + 2 * nb;
        #pragma unroll 2
        for (int b = 0; b < BATCH; ++b) {
          float4 t4 = *(const float4*)(trp + (size_t)b * INQ);
          float4 g4 = *(const float4*)(imp + (size_t)b * INQ);
          float4 sp = *(const float4*)(spp + (size_t)b * 2 * NP);
          float ap0 = 1e-3f * sp.x, am0 = 1e-3f * sp.y;
          float ap1 = 1e-3f * sp.z, am1 = 1e-3f * sp.w;
          a00 = fmaf(t4.x, ap0, fmaf(g4.x, -am0, a00));
          a01 = fmaf(t4.x, ap1, fmaf(g4.x, -am1, a01));
          a10 = fmaf(t4.y, ap0, fmaf(g4.y, -am0, a10));
          a11 = fmaf(t4.y, ap1, fmaf(g4.y, -am1, a11));
          a20 = fmaf(t4.z, ap0, fmaf(g4.z, -am0, a20));
          a21 = fmaf(t4.z, ap1, fmaf(g4.z, -am1, a21));
          a30 = fmaf(t4.w, ap0, fmaf(g4.w, -am0, a30));
          a31 = fmaf(t4.w, ap1, fmaf(g4.w, -am1, a31));
        }
        float accs[4][2] = {{a00,a01},{a10,a11},{a20,a21},{a30,a31}};
        #pragma unroll
        for (int k = 0; k < 4; ++k) {
          float* wp = Wt + (size_t)(ib + k) * NP + nb;
          float2 w2 = *(float2*)wp;
          w2.x = fminf(fmaxf(w2.x + accs[k][0], 0.f), 1.f);
          w2.y = fminf(fmaxf(w2.y + accs[k][1], 0.f), 1.f);
          *(float2*)wp = w2;
        }
      }
    }
    gbar(bar);
  }

  // ---- final: W_out[n][i] = Wt[i][n] ----
  for (int e = blk * NTHR + tid; e < NOUT * INQ; e += GRID * NTHR) {
    int n = e / INQ, i = e % INQ;
    Wout[e] = Wt[(size_t)i * NP + n];
  }
}

extern "C" void kernel_launch(void* const* d_in, const int* in_sizes, int n_in,
                              void* d_out, int out_size, void* d_ws, size_t ws_size,
                              hipStream_t stream) {
  const float* img = (const float*)d_in[0];
  const float* W   = (const float*)d_in[1];
  float* out = (float*)d_out;
  float* ws  = (float*)d_ws;

  // zero all state + barrier words (graph-capture safe)
  hipMemsetAsync(d_ws, 0, (size_t)WS_FLOATS * sizeof(float), stream);

  void* args[] = { (void*)&img, (void*)&W, (void*)&out, (void*)&ws };
  hipLaunchCooperativeKernel((const void*)snn_kernel, dim3(GRID), dim3(NTHR),
                             args, 0, stream);
}

// Round 2
// 16621.317 us; speedup vs baseline: 2.1248x; 2.1248x over previous
//
#include <hip/hip_runtime.h>

// SNN-MNIST forward + STDP, MI355X persistent cooperative kernel.
// Round 2: LDS-staged phase 2 w/ async global_load_lds + raw barriers,
// unroll-8 sparse gather in phase 1, leaner grid barrier (no explicit fences).

#define T_STEPS 200
#define BATCH   256
#define INQ     784
#define NOUT    400
#define NP      512
#define GRID    256
#define NTHR    256

// ws layout (float offsets)
#define OFF_WT    0            // Wt [785][512] (row 784 = zero pad for gather)
#define OFF_SYN   401920       // syn [256][512]
#define OFF_MEM   532992       // mem [256][512]
#define OFF_SPPO  664064       // interleaved (spk,post): [256][1024]
#define OFF_TRA   926208       // trA [256][784]
#define OFF_TRB   1126912      // trB [256][784]
#define OFF_WIN   1327616      // int win[256]
#define OFF_FLAGS 1327872      // int flags[256]
#define OFF_BAR   1328128      // unsigned bar[8]
#define WS_FLOATS 1328136

__device__ __forceinline__ void gl_lds16(const float* g, float* l) {
  __builtin_amdgcn_global_load_lds(
      (const __attribute__((address_space(1))) void*)g,
      (__attribute__((address_space(3))) void*)l, 16, 0, 0);
}

// Grid barrier. The ACQ_REL fetch_add carries each block's release; pollers do
// one explicit ACQUIRE load on exit. No full __threadfence (halves wbl2/inv).
__device__ __forceinline__ void gbar(unsigned* bar) {
  __syncthreads();
  if (threadIdx.x == 0) {
    unsigned g = __hip_atomic_load(bar + 1, __ATOMIC_RELAXED, __HIP_MEMORY_SCOPE_AGENT);
    unsigned a = __hip_atomic_fetch_add(bar, 1u, __ATOMIC_ACQ_REL, __HIP_MEMORY_SCOPE_AGENT);
    if (a == GRID - 1u) {
      __hip_atomic_store(bar, 0u, __ATOMIC_RELAXED, __HIP_MEMORY_SCOPE_AGENT);
      __hip_atomic_store(bar + 1, g + 1u, __ATOMIC_RELEASE, __HIP_MEMORY_SCOPE_AGENT);
    } else {
      while (__hip_atomic_load(bar + 1, __ATOMIC_RELAXED, __HIP_MEMORY_SCOPE_AGENT) == g)
        __builtin_amdgcn_s_sleep(2);
      (void)__hip_atomic_load(bar + 1, __ATOMIC_ACQUIRE, __HIP_MEMORY_SCOPE_AGENT);
    }
  }
  __syncthreads();
}

__global__ void __launch_bounds__(NTHR) snn_kernel(
    const float* __restrict__ img,   // [200][256][784]
    const float* __restrict__ Win,   // [400][784]
    float* __restrict__ out,         // mem_rec | spk_rec | W_final
    float* ws)
{
  float* Wt    = ws + OFF_WT;
  float* syn   = ws + OFF_SYN;
  float* mem   = ws + OFF_MEM;
  float* sppo  = ws + OFF_SPPO;
  float* trA   = ws + OFF_TRA;
  float* trB   = ws + OFF_TRB;
  int*   win   = (int*)(ws + OFF_WIN);
  int*   flags = (int*)(ws + OFF_FLAGS);
  unsigned* bar = (unsigned*)(ws + OFF_BAR);

  float* mem_rec = out;
  float* spk_rec = out + (size_t)T_STEPS * BATCH * NOUT;
  float* Wout    = out + (size_t)2 * T_STEPS * BATCH * NOUT;

  const int tid = threadIdx.x;
  const int blk = blockIdx.x;

  __shared__ int s_list[800];
  __shared__ int s_cnt;
  __shared__ int s_red[NTHR];
  // phase-2 staging: [buf][ tr 0..2047 | img 2048..4095 | sppo 4096..6143 ]
  // each region: 32 b-rows x 64 floats
  __shared__ float stg[2][6144];

  // ---- init: Wt[i][n] = Win[n][i] (ws memset to 0; pad row 784 stays 0) ----
  for (int e = blk * NTHR + tid; e < NOUT * INQ; e += GRID * NTHR) {
    int n = e / INQ, i = e % INQ;
    Wt[(size_t)i * NP + n] = Win[e];
  }
  gbar(bar);

  for (int t = 0; t < T_STEPS; ++t) {
    float* trC = (t & 1) ? trB : trA;   // pre_traces[t]
    float* trN = (t & 1) ? trA : trB;   // pre_traces[t+1]

    // ================= phase 1: block b = batch row =================
    {
      const int b = blk;
      const float* imrow = img + ((size_t)t * BATCH + b) * INQ;
      float* trCrow = trC + (size_t)b * INQ;
      float* trNrow = trN + (size_t)b * INQ;
      if (tid >= 64) {
        // waves 1-3: trace recurrence tr_{t+1} = 0.9*tr_t + img_t
        for (int i = tid - 64; i < INQ; i += NTHR - 64)
          trNrow[i] = fmaf(0.9f, trCrow[i], imrow[i]);
      } else {
        // wave 0: ordered active-index compaction, padded to multiple of 8
        int base = 0;
        for (int c = 0; c < INQ; c += 64) {
          int i = c + tid;
          bool act = (i < INQ) && (imrow[i] != 0.0f);
          unsigned long long m = __ballot(act);
          if (act) s_list[base + (int)__popcll(m & ((1ull << tid) - 1ull))] = i;
          base += (int)__popcll(m);
        }
        if (tid == 0) {
          int cr = (base + 7) & ~7;
          for (int j = base; j < cr; ++j) s_list[j] = 784;  // zero pad row
          s_cnt = cr;
        }
      }
      __syncthreads();
      const int cnt = s_cnt;            // multiple of 8
      const int anyPrev = (t > 0) ? flags[t - 1] : 0;
      const int wPrev = win[b];
      int localmin = 0x7fffffff;

      if (tid < 200) {
        const int n0 = tid * 2;
        const size_t sidx = (size_t)b * NP + n0;
        float2 sv = *(float2*)(syn + sidx);
        if (anyPrev) {
          if (n0     != wPrev) sv.x -= 0.1f;
          if (n0 + 1 != wPrev) sv.y -= 0.1f;
        }
        float c0 = 0.f, c1 = 0.f;
        for (int j = 0; j < cnt; j += 8) {   // 8 loads in flight per round
          float2 w0 = *(const float2*)(Wt + (size_t)s_list[j+0] * NP + n0);
          float2 w1 = *(const float2*)(Wt + (size_t)s_list[j+1] * NP + n0);
          float2 w2 = *(const float2*)(Wt + (size_t)s_list[j+2] * NP + n0);
          float2 w3 = *(const float2*)(Wt + (size_t)s_list[j+3] * NP + n0);
          float2 w4 = *(const float2*)(Wt + (size_t)s_list[j+4] * NP + n0);
          float2 w5 = *(const float2*)(Wt + (size_t)s_list[j+5] * NP + n0);
          float2 w6 = *(const float2*)(Wt + (size_t)s_list[j+6] * NP + n0);
          float2 w7 = *(const float2*)(Wt + (size_t)s_list[j+7] * NP + n0);
          // keep exact ascending-index add order (pads add +0.0f exactly)
          c0 += w0.x; c1 += w0.y;  c0 += w1.x; c1 += w1.y;
          c0 += w2.x; c1 += w2.y;  c0 += w3.x; c1 += w3.y;
          c0 += w4.x; c1 += w4.y;  c0 += w5.x; c1 += w5.y;
          c0 += w6.x; c1 += w6.y;  c0 += w7.x; c1 += w7.y;
        }
        float2 mv = *(float2*)(mem + sidx);
        float syn0 = fmaf(0.9f, sv.x, c0);
        float syn1 = fmaf(0.9f, sv.y, c1);
        float r0 = (mv.x > 1.0f) ? 1.0f : 0.0f;
        float r1 = (mv.y > 1.0f) ? 1.0f : 0.0f;
        float m0 = fmaf(0.8f, mv.x, syn0) - r0;
        float m1 = fmaf(0.8f, mv.y, syn1) - r1;
        float s0 = (m0 > 1.0f) ? 1.0f : 0.0f;
        float s1 = (m1 > 1.0f) ? 1.0f : 0.0f;
        *(float2*)(syn + sidx) = make_float2(syn0, syn1);
        *(float2*)(mem + sidx) = make_float2(m0, m1);
        float4 sp = *(float4*)(sppo + (size_t)b * 2 * NP + 2 * n0);
        float p0 = fmaf(0.9f, sp.y, s0);
        float p1 = fmaf(0.9f, sp.w, s1);
        *(float4*)(sppo + (size_t)b * 2 * NP + 2 * n0) = make_float4(s0, p0, s1, p1);
        const size_t ridx = (size_t)t * BATCH * NOUT + (size_t)b * NOUT + n0;
        *(float2*)(mem_rec + ridx) = make_float2(m0, m1);
        *(float2*)(spk_rec + ridx) = make_float2(s0, s1);
        if      (s0 != 0.f) localmin = n0;
        else if (s1 != 0.f) localmin = n0 + 1;
      }
      s_red[tid] = localmin;
      __syncthreads();
      for (int o = NTHR / 2; o > 0; o >>= 1) {
        if (tid < o) s_red[tid] = min(s_red[tid], s_red[tid + o]);
        __syncthreads();
      }
      if (tid == 0) {
        int w = s_red[0];
        win[b] = (w == 0x7fffffff) ? 0 : w;
        if (w != 0x7fffffff) atomicOr(&flags[t], 1);
      }
    }
    gbar(bar);

    // ================= phase 2: STDP weight update (LDS-staged) =============
    if (blk < 169) {
      const int bi = blk / 13, bn = blk % 13;
      const int ib0 = bi * 64, nb0 = bn * 32;
      const int w = tid >> 6, l = tid & 63;
      // staging lane geometry: lane covers row brow0 (+q*16), cols (l&15)*4
      const int brow0 = w * 4 + (l >> 4);
      int icol = ib0 + (l & 15) * 4;
      if (icol > INQ - 4) icol = INQ - 4;         // clamp (garbage, unused)
      const int scol = 2 * nb0 + (l & 15) * 4;
      const float* imgt = img + (size_t)t * BATCH * INQ;

      const int ib = ib0 + (tid >> 4) * 4;
      const int nb = nb0 + (tid & 15) * 2;
      const bool active = (ib < INQ) && (nb < NOUT);
      const int loff = (tid >> 4) * 4;            // i-offset within LDS row
      const int soff = (tid & 15) * 4;            // sppo offset within LDS row

      float a00=0,a01=0,a10=0,a11=0,a20=0,a21=0,a30=0,a31=0;

      // stage chunk c (32 b-rows) into buf: 6 global_load_lds per wave
      #define STG(c, buf) {                                                     \
        int b0_ = (c) * 32;                                                     \
        for (int q = 0; q < 2; ++q) {                                           \
          int br = b0_ + q * 16 + brow0;                                        \
          float* dst = &stg[buf][(q * 16 + w * 4) * 64];                        \
          gl_lds16(trC  + (size_t)br * INQ  + icol, dst);                       \
          gl_lds16(imgt + (size_t)br * INQ  + icol, dst + 2048);                \
          gl_lds16(sppo + (size_t)br * 1024 + scol, dst + 4096);                \
        }                                                                       \
      }

      STG(0, 0);
      for (int c = 0; c < 8; ++c) {
        const int buf = c & 1;
        if (c < 7) {
          STG(c + 1, buf ^ 1);
          __builtin_amdgcn_s_waitcnt(0x0F76);     // vmcnt(6): chunk c landed
        } else {
          __builtin_amdgcn_s_waitcnt(0x0F70);     // vmcnt(0)
        }
        __builtin_amdgcn_s_barrier();             // all waves' parts ready
        if (active) {
          const float* Ltr = &stg[buf][loff];
          const float* Lim = &stg[buf][2048 + loff];
          const float* Lsp = &stg[buf][4096 + soff];
          #pragma unroll 4
          for (int bb = 0; bb < 32; ++bb) {       // b ascending: same order
            float4 t4 = *(const float4*)(Ltr + bb * 64);
            float4 g4 = *(const float4*)(Lim + bb * 64);
            float4 sp = *(const float4*)(Lsp + bb * 64);
            float ap0 = 1e-3f * sp.x, am0 = 1e-3f * sp.y;
            float ap1 = 1e-3f * sp.z, am1 = 1e-3f * sp.w;
            a00 = fmaf(t4.x, ap0, fmaf(g4.x, -am0, a00));
            a01 = fmaf(t4.x, ap1, fmaf(g4.x, -am1, a01));
            a10 = fmaf(t4.y, ap0, fmaf(g4.y, -am0, a10));
            a11 = fmaf(t4.y, ap1, fmaf(g4.y, -am1, a11));
            a20 = fmaf(t4.z, ap0, fmaf(g4.z, -am0, a20));
            a21 = fmaf(t4.z, ap1, fmaf(g4.z, -am1, a21));
            a30 = fmaf(t4.w, ap0, fmaf(g4.w, -am0, a30));
            a31 = fmaf(t4.w, ap1, fmaf(g4.w, -am1, a31));
          }
        }
        __builtin_amdgcn_s_waitcnt(0xC07F);       // lgkmcnt(0) only
        __builtin_amdgcn_s_barrier();             // guard buf reuse
      }
      #undef STG

      if (active) {
        float accs[4][2] = {{a00,a01},{a10,a11},{a20,a21},{a30,a31}};
        #pragma unroll
        for (int k = 0; k < 4; ++k) {
          float* wp = Wt + (size_t)(ib + k) * NP + nb;
          float2 w2 = *(float2*)wp;
          w2.x = fminf(fmaxf(w2.x + accs[k][0], 0.f), 1.f);
          w2.y = fminf(fmaxf(w2.y + accs[k][1], 0.f), 1.f);
          *(float2*)wp = w2;
        }
      }
    }
    gbar(bar);
  }

  // ---- final: W_out[n][i] = Wt[i][n] ----
  for (int e = blk * NTHR + tid; e < NOUT * INQ; e += GRID * NTHR) {
    int n = e / INQ, i = e % INQ;
    Wout[e] = Wt[(size_t)i * NP + n];
  }
}

extern "C" void kernel_launch(void* const* d_in, const int* in_sizes, int n_in,
                              void* d_out, int out_size, void* d_ws, size_t ws_size,
                              hipStream_t stream) {
  const float* img = (const float*)d_in[0];
  const float* W   = (const float*)d_in[1];
  float* out = (float*)d_out;
  float* ws  = (float*)d_ws;

  hipMemsetAsync(d_ws, 0, (size_t)WS_FLOATS * sizeof(float), stream);

  void* args[] = { (void*)&img, (void*)&W, (void*)&out, (void*)&ws };
  hipLaunchCooperativeKernel((const void*)snn_kernel, dim3(GRID), dim3(NTHR),
                             args, 0, stream);
}

// Round 3
// 9815.221 us; speedup vs baseline: 3.5981x; 1.6934x over previous
//
#include <hip/hip_runtime.h>

// SNN-MNIST forward + STDP, MI355X persistent cooperative kernel.
// Round 3: fence-free grid barrier (relaxed monotonic counter) + explicit
// sc1 (agent-coherent, L3-served) accesses for cross-XCD data only.
// Block-private state stays warm in per-XCD L2 (no more buffer_inv).

#define T_STEPS 200
#define BATCH   256
#define INQ     784
#define NOUT    400
#define NP      512
#define GRID    256
#define NTHR    256

// ws layout (float offsets)
#define OFF_WT    0            // Wt [785][512] (row 784 = zero pad for gather)
#define OFF_SYN   401920       // syn [256][512]         (block-private)
#define OFF_MEM   532992       // mem [256][512]         (block-private)
#define OFF_SPPO  664064       // interleaved (spk,post): [256][1024]  (sc1)
#define OFF_TRA   926208       // trA [256][784]         (sc1)
#define OFF_TRB   1126912      // trB [256][784]         (sc1)
#define OFF_WIN   1327616      // int win[256]           (block-private)
#define OFF_FLAGS 1327872      // int flags[256]         (sc1)
#define OFF_BAR   1328128      // unsigned bar[8]
#define WS_FLOATS 1328136

// ---- agent-coherent (sc1) access helpers: L2 read-through / write-through ---
__device__ __forceinline__ float ld_coh(const float* p) {
  return __hip_atomic_load(p, __ATOMIC_RELAXED, __HIP_MEMORY_SCOPE_AGENT);
}
__device__ __forceinline__ float2 ld_coh2(const float* p) {
  union { unsigned long long u; float2 f; } c;
  c.u = __hip_atomic_load((const unsigned long long*)p, __ATOMIC_RELAXED,
                          __HIP_MEMORY_SCOPE_AGENT);
  return c.f;
}
__device__ __forceinline__ void st_coh(float* p, float v) {
  __hip_atomic_store(p, v, __ATOMIC_RELAXED, __HIP_MEMORY_SCOPE_AGENT);
}
__device__ __forceinline__ void st_coh2(float* p, float2 v) {
  union { unsigned long long u; float2 f; } c; c.f = v;
  __hip_atomic_store((unsigned long long*)p, c.u, __ATOMIC_RELAXED,
                     __HIP_MEMORY_SCOPE_AGENT);
}

__device__ __forceinline__ void gl_lds16(const float* g, float* l) {       // cached
  __builtin_amdgcn_global_load_lds(
      (const __attribute__((address_space(1))) void*)g,
      (__attribute__((address_space(3))) void*)l, 16, 0, 0);
}
__device__ __forceinline__ void gl_lds16c(const float* g, float* l) {      // sc1
  __builtin_amdgcn_global_load_lds(
      (const __attribute__((address_space(1))) void*)g,
      (__attribute__((address_space(3))) void*)l, 16, 0, 0x10);
}

// Fence-free grid barrier: monotonic relaxed counter. __syncthreads() drains
// each wave's vm queue (write-through stores globally visible) before arrival.
__device__ __forceinline__ void gbar(unsigned* bar, unsigned target) {
  __syncthreads();
  if (threadIdx.x == 0) {
    __hip_atomic_fetch_add(bar, 1u, __ATOMIC_RELAXED, __HIP_MEMORY_SCOPE_AGENT);
    while (__hip_atomic_load(bar, __ATOMIC_RELAXED, __HIP_MEMORY_SCOPE_AGENT) < target)
      __builtin_amdgcn_s_sleep(4);
  }
  __syncthreads();
}

__global__ void __launch_bounds__(NTHR) snn_kernel(
    const float* __restrict__ img,   // [200][256][784]
    const float* __restrict__ Win,   // [400][784]
    float* __restrict__ out,         // mem_rec | spk_rec | W_final
    float* ws)
{
  float* Wt    = ws + OFF_WT;
  float* syn   = ws + OFF_SYN;
  float* mem   = ws + OFF_MEM;
  float* sppo  = ws + OFF_SPPO;
  float* trA   = ws + OFF_TRA;
  float* trB   = ws + OFF_TRB;
  int*   win   = (int*)(ws + OFF_WIN);
  unsigned* flags = (unsigned*)(ws + OFF_FLAGS);
  unsigned* bar   = (unsigned*)(ws + OFF_BAR);

  float* mem_rec = out;
  float* spk_rec = out + (size_t)T_STEPS * BATCH * NOUT;
  float* Wout    = out + (size_t)2 * T_STEPS * BATCH * NOUT;

  const int tid = threadIdx.x;
  const int blk = blockIdx.x;
  unsigned bt = 0;                    // barrier target accumulator

  __shared__ int s_list[800];
  __shared__ int s_cnt;
  __shared__ int s_red[NTHR];
  __shared__ float stg[2][6144];      // [buf][tr | img | sppo], 32 b-rows x 64

  // ---- init: Wt[i][n] = Win[n][i], written coherently ----
  for (int e = blk * NTHR + tid; e < NOUT * INQ; e += GRID * NTHR) {
    int n = e / INQ, i = e % INQ;
    st_coh(Wt + (size_t)i * NP + n, Win[e]);
  }
  bt += GRID; gbar(bar, bt);

  for (int t = 0; t < T_STEPS; ++t) {
    float* trC = (t & 1) ? trB : trA;   // pre_traces[t]
    float* trN = (t & 1) ? trA : trB;   // pre_traces[t+1]

    // ================= phase 1: block b = batch row =================
    {
      const int b = blk;
      const float* imrow = img + ((size_t)t * BATCH + b) * INQ;
      float* trCrow = trC + (size_t)b * INQ;
      float* trNrow = trN + (size_t)b * INQ;
      if (tid >= 64) {
        // waves 1-3: trace recurrence tr_{t+1} = 0.9*tr_t + img_t
        for (int i = tid - 64; i < INQ; i += NTHR - 64)
          st_coh(trNrow + i, fmaf(0.9f, ld_coh(trCrow + i), imrow[i]));
      } else {
        // wave 0: ordered active-index compaction, padded to multiple of 8
        int base = 0;
        for (int c = 0; c < INQ; c += 64) {
          int i = c + tid;
          bool act = (i < INQ) && (imrow[i] != 0.0f);
          unsigned long long m = __ballot(act);
          if (act) s_list[base + (int)__popcll(m & ((1ull << tid) - 1ull))] = i;
          base += (int)__popcll(m);
        }
        if (tid == 0) {
          int cr = (base + 7) & ~7;
          for (int j = base; j < cr; ++j) s_list[j] = 784;  // zero pad row
          s_cnt = cr;
        }
      }
      __syncthreads();
      const int cnt = s_cnt;            // multiple of 8
      const int anyPrev = (t > 0)
          ? (int)__hip_atomic_load(&flags[t - 1], __ATOMIC_RELAXED, __HIP_MEMORY_SCOPE_AGENT)
          : 0;
      const int wPrev = win[b];
      int localmin = 0x7fffffff;

      if (tid < 200) {
        const int n0 = tid * 2;
        const size_t sidx = (size_t)b * NP + n0;
        float2 sv = *(float2*)(syn + sidx);
        if (anyPrev) {
          if (n0     != wPrev) sv.x -= 0.1f;
          if (n0 + 1 != wPrev) sv.y -= 0.1f;
        }
        float c0 = 0.f, c1 = 0.f;
        for (int j = 0; j < cnt; j += 8) {   // 8 coherent loads in flight
          float2 w0 = ld_coh2(Wt + (size_t)s_list[j+0] * NP + n0);
          float2 w1 = ld_coh2(Wt + (size_t)s_list[j+1] * NP + n0);
          float2 w2 = ld_coh2(Wt + (size_t)s_list[j+2] * NP + n0);
          float2 w3 = ld_coh2(Wt + (size_t)s_list[j+3] * NP + n0);
          float2 w4 = ld_coh2(Wt + (size_t)s_list[j+4] * NP + n0);
          float2 w5 = ld_coh2(Wt + (size_t)s_list[j+5] * NP + n0);
          float2 w6 = ld_coh2(Wt + (size_t)s_list[j+6] * NP + n0);
          float2 w7 = ld_coh2(Wt + (size_t)s_list[j+7] * NP + n0);
          c0 += w0.x; c1 += w0.y;  c0 += w1.x; c1 += w1.y;
          c0 += w2.x; c1 += w2.y;  c0 += w3.x; c1 += w3.y;
          c0 += w4.x; c1 += w4.y;  c0 += w5.x; c1 += w5.y;
          c0 += w6.x; c1 += w6.y;  c0 += w7.x; c1 += w7.y;
        }
        float2 mv = *(float2*)(mem + sidx);
        float syn0 = fmaf(0.9f, sv.x, c0);
        float syn1 = fmaf(0.9f, sv.y, c1);
        float r0 = (mv.x > 1.0f) ? 1.0f : 0.0f;
        float r1 = (mv.y > 1.0f) ? 1.0f : 0.0f;
        float m0 = fmaf(0.8f, mv.x, syn0) - r0;
        float m1 = fmaf(0.8f, mv.y, syn1) - r1;
        float s0 = (m0 > 1.0f) ? 1.0f : 0.0f;
        float s1 = (m1 > 1.0f) ? 1.0f : 0.0f;
        *(float2*)(syn + sidx) = make_float2(syn0, syn1);
        *(float2*)(mem + sidx) = make_float2(m0, m1);
        // post trace; sppo is cross-XCD -> sc1 both ways
        float2 spA = ld_coh2(sppo + (size_t)b * 2 * NP + 2 * n0);
        float2 spB = ld_coh2(sppo + (size_t)b * 2 * NP + 2 * n0 + 2);
        float p0 = fmaf(0.9f, spA.y, s0);
        float p1 = fmaf(0.9f, spB.y, s1);
        st_coh2(sppo + (size_t)b * 2 * NP + 2 * n0,     make_float2(s0, p0));
        st_coh2(sppo + (size_t)b * 2 * NP + 2 * n0 + 2, make_float2(s1, p1));
        const size_t ridx = (size_t)t * BATCH * NOUT + (size_t)b * NOUT + n0;
        *(float2*)(mem_rec + ridx) = make_float2(m0, m1);
        *(float2*)(spk_rec + ridx) = make_float2(s0, s1);
        if      (s0 != 0.f) localmin = n0;
        else if (s1 != 0.f) localmin = n0 + 1;
      }
      s_red[tid] = localmin;
      __syncthreads();
      for (int o = NTHR / 2; o > 0; o >>= 1) {
        if (tid < o) s_red[tid] = min(s_red[tid], s_red[tid + o]);
        __syncthreads();
      }
      if (tid == 0) {
        int w = s_red[0];
        win[b] = (w == 0x7fffffff) ? 0 : w;
        if (w != 0x7fffffff)
          __hip_atomic_fetch_or(&flags[t], 1u, __ATOMIC_RELAXED, __HIP_MEMORY_SCOPE_AGENT);
      }
    }
    bt += GRID; gbar(bar, bt);

    // ================= phase 2: STDP weight update (LDS-staged) =============
    if (blk < 169) {
      const int bi = blk / 13, bn = blk % 13;
      const int ib0 = bi * 64, nb0 = bn * 32;
      const int w = tid >> 6, l = tid & 63;
      const int brow0 = w * 4 + (l >> 4);
      int icol = ib0 + (l & 15) * 4;
      if (icol > INQ - 4) icol = INQ - 4;         // clamp (garbage, unused)
      const int scol = 2 * nb0 + (l & 15) * 4;
      const float* imgt = img + (size_t)t * BATCH * INQ;

      const int ib = ib0 + (tid >> 4) * 4;
      const int nb = nb0 + (tid & 15) * 2;
      const bool active = (ib < INQ) && (nb < NOUT);
      const int loff = (tid >> 4) * 4;
      const int soff = (tid & 15) * 4;

      float a00=0,a01=0,a10=0,a11=0,a20=0,a21=0,a30=0,a31=0;

      // stage chunk c (32 b-rows): tr/sppo coherent (sc1), img cached
      #define STG(c, buf) {                                                     \
        int b0_ = (c) * 32;                                                     \
        for (int q = 0; q < 2; ++q) {                                           \
          int br = b0_ + q * 16 + brow0;                                        \
          float* dst = &stg[buf][(q * 16 + w * 4) * 64];                        \
          gl_lds16c(trC  + (size_t)br * INQ  + icol, dst);                      \
          gl_lds16 (imgt + (size_t)br * INQ  + icol, dst + 2048);               \
          gl_lds16c(sppo + (size_t)br * 1024 + scol, dst + 4096);               \
        }                                                                       \
      }

      STG(0, 0);
      for (int c = 0; c < 8; ++c) {
        const int buf = c & 1;
        if (c < 7) {
          STG(c + 1, buf ^ 1);
          __builtin_amdgcn_s_waitcnt(0x0F76);     // vmcnt(6): chunk c landed
        } else {
          __builtin_amdgcn_s_waitcnt(0x0F70);     // vmcnt(0)
        }
        __builtin_amdgcn_s_barrier();
        if (active) {
          const float* Ltr = &stg[buf][loff];
          const float* Lim = &stg[buf][2048 + loff];
          const float* Lsp = &stg[buf][4096 + soff];
          #pragma unroll 4
          for (int bb = 0; bb < 32; ++bb) {       // b ascending: exact order
            float4 t4 = *(const float4*)(Ltr + bb * 64);
            float4 g4 = *(const float4*)(Lim + bb * 64);
            float4 sp = *(const float4*)(Lsp + bb * 64);
            float ap0 = 1e-3f * sp.x, am0 = 1e-3f * sp.y;
            float ap1 = 1e-3f * sp.z, am1 = 1e-3f * sp.w;
            a00 = fmaf(t4.x, ap0, fmaf(g4.x, -am0, a00));
            a01 = fmaf(t4.x, ap1, fmaf(g4.x, -am1, a01));
            a10 = fmaf(t4.y, ap0, fmaf(g4.y, -am0, a10));
            a11 = fmaf(t4.y, ap1, fmaf(g4.y, -am1, a11));
            a20 = fmaf(t4.z, ap0, fmaf(g4.z, -am0, a20));
            a21 = fmaf(t4.z, ap1, fmaf(g4.z, -am1, a21));
            a30 = fmaf(t4.w, ap0, fmaf(g4.w, -am0, a30));
            a31 = fmaf(t4.w, ap1, fmaf(g4.w, -am1, a31));
          }
        }
        __builtin_amdgcn_s_waitcnt(0xC07F);       // lgkmcnt(0) only
        __builtin_amdgcn_s_barrier();
      }
      #undef STG

      if (active) {
        float accs[4][2] = {{a00,a01},{a10,a11},{a20,a21},{a30,a31}};
        #pragma unroll
        for (int k = 0; k < 4; ++k) {
          float* wp = Wt + (size_t)(ib + k) * NP + nb;
          float2 w2 = ld_coh2(wp);                // coherent RMW of Wt
          w2.x = fminf(fmaxf(w2.x + accs[k][0], 0.f), 1.f);
          w2.y = fminf(fmaxf(w2.y + accs[k][1], 0.f), 1.f);
          st_coh2(wp, w2);
        }
      }
    }
    bt += GRID; gbar(bar, bt);
  }

  // ---- final: W_out[n][i] = Wt[i][n] ----
  for (int e = blk * NTHR + tid; e < NOUT * INQ; e += GRID * NTHR) {
    int n = e / INQ, i = e % INQ;
    Wout[e] = ld_coh(Wt + (size_t)i * NP + n);
  }
}

extern "C" void kernel_launch(void* const* d_in, const int* in_sizes, int n_in,
                              void* d_out, int out_size, void* d_ws, size_t ws_size,
                              hipStream_t stream) {
  const float* img = (const float*)d_in[0];
  const float* W   = (const float*)d_in[1];
  float* out = (float*)d_out;
  float* ws  = (float*)d_ws;

  hipMemsetAsync(d_ws, 0, (size_t)WS_FLOATS * sizeof(float), stream);

  void* args[] = { (void*)&img, (void*)&W, (void*)&out, (void*)&ws };
  hipLaunchCooperativeKernel((const void*)snn_kernel, dim3(GRID), dim3(NTHR),
                             args, 0, stream);
}

// Round 4
// 7716.711 us; speedup vs baseline: 4.5766x; 1.2719x over previous
//
#include <hip/hip_runtime.h>

// SNN-MNIST forward + STDP, MI355X persistent cooperative kernel.
// Round 4: hierarchical fence-free grid barrier (32 groups x 8 blocks,
// monotonic counters, spread cache lines) replacing the flat 256-wide
// single-line counter (which serialized ~256 agent RMWs per barrier).

#define T_STEPS 200
#define BATCH   256
#define INQ     784
#define NOUT    400
#define NP      512
#define GRID    256
#define NTHR    256

// ws layout (float offsets)
#define OFF_WT    0            // Wt [785][512] (row 784 = zero pad for gather)
#define OFF_SYN   401920       // syn [256][512]         (block-private)
#define OFF_MEM   532992       // mem [256][512]         (block-private)
#define OFF_SPPO  664064       // interleaved (spk,post): [256][1024]  (sc1)
#define OFF_TRA   926208       // trA [256][784]         (sc1)
#define OFF_TRB   1126912      // trB [256][784]         (sc1)
#define OFF_WIN   1327616      // int win[256]           (block-private)
#define OFF_FLAGS 1327872      // int flags[256]         (sc1)
#define OFF_BAR   1328128      // unsigned bar[4096]: hierarchical barrier
#define WS_FLOATS 1332224

// ---- agent-coherent (sc1) access helpers: L2 read-through / write-through ---
__device__ __forceinline__ float ld_coh(const float* p) {
  return __hip_atomic_load(p, __ATOMIC_RELAXED, __HIP_MEMORY_SCOPE_AGENT);
}
__device__ __forceinline__ float2 ld_coh2(const float* p) {
  union { unsigned long long u; float2 f; } c;
  c.u = __hip_atomic_load((const unsigned long long*)p, __ATOMIC_RELAXED,
                          __HIP_MEMORY_SCOPE_AGENT);
  return c.f;
}
__device__ __forceinline__ void st_coh(float* p, float v) {
  __hip_atomic_store(p, v, __ATOMIC_RELAXED, __HIP_MEMORY_SCOPE_AGENT);
}
__device__ __forceinline__ void st_coh2(float* p, float2 v) {
  union { unsigned long long u; float2 f; } c; c.f = v;
  __hip_atomic_store((unsigned long long*)p, c.u, __ATOMIC_RELAXED,
                     __HIP_MEMORY_SCOPE_AGENT);
}

__device__ __forceinline__ void gl_lds16(const float* g, float* l) {       // cached
  __builtin_amdgcn_global_load_lds(
      (const __attribute__((address_space(1))) void*)g,
      (__attribute__((address_space(3))) void*)l, 16, 0, 0);
}
__device__ __forceinline__ void gl_lds16c(const float* g, float* l) {      // sc1
  __builtin_amdgcn_global_load_lds(
      (const __attribute__((address_space(1))) void*)g,
      (__attribute__((address_space(3))) void*)l, 16, 0, 0x10);
}

// Hierarchical fence-free grid barrier, k = 1-based barrier ordinal.
// Level 1: 32 group counters (8 blocks each), 256 B apart. Level 2: 32-wide
// root. Monotonic counters (no reset/ABA). __syncthreads() before arrival
// drains vmcnt, making each block's write-through stores globally visible.
__device__ __forceinline__ void gbar(unsigned* bar, unsigned k, int blk) {
  __syncthreads();
  if (threadIdx.x == 0) {
    const int g = blk >> 3;
    unsigned* garr = bar + g * 64;
    unsigned* ggen = bar + g * 64 + 32;
    unsigned* rarr = bar + 32 * 64;
    unsigned* rgen = bar + 32 * 64 + 32;
    unsigned a = __hip_atomic_fetch_add(garr, 1u, __ATOMIC_RELAXED,
                                        __HIP_MEMORY_SCOPE_AGENT);
    if (a + 1u == k * 8u) {          // group leader = last arriver
      unsigned r = __hip_atomic_fetch_add(rarr, 1u, __ATOMIC_RELAXED,
                                          __HIP_MEMORY_SCOPE_AGENT);
      if (r + 1u == k * 32u) {       // root completer
        __hip_atomic_store(rgen, k, __ATOMIC_RELAXED, __HIP_MEMORY_SCOPE_AGENT);
      } else {
        while (__hip_atomic_load(rgen, __ATOMIC_RELAXED,
                                 __HIP_MEMORY_SCOPE_AGENT) < k)
          __builtin_amdgcn_s_sleep(1);
      }
      __hip_atomic_store(ggen, k, __ATOMIC_RELAXED, __HIP_MEMORY_SCOPE_AGENT);
    } else {
      while (__hip_atomic_load(ggen, __ATOMIC_RELAXED,
                               __HIP_MEMORY_SCOPE_AGENT) < k)
        __builtin_amdgcn_s_sleep(1);
    }
  }
  __syncthreads();
}

__global__ void __launch_bounds__(NTHR) snn_kernel(
    const float* __restrict__ img,   // [200][256][784]
    const float* __restrict__ Win,   // [400][784]
    float* __restrict__ out,         // mem_rec | spk_rec | W_final
    float* ws)
{
  float* Wt    = ws + OFF_WT;
  float* syn   = ws + OFF_SYN;
  float* mem   = ws + OFF_MEM;
  float* sppo  = ws + OFF_SPPO;
  float* trA   = ws + OFF_TRA;
  float* trB   = ws + OFF_TRB;
  int*   win   = (int*)(ws + OFF_WIN);
  unsigned* flags = (unsigned*)(ws + OFF_FLAGS);
  unsigned* bar   = (unsigned*)(ws + OFF_BAR);

  float* mem_rec = out;
  float* spk_rec = out + (size_t)T_STEPS * BATCH * NOUT;
  float* Wout    = out + (size_t)2 * T_STEPS * BATCH * NOUT;

  const int tid = threadIdx.x;
  const int blk = blockIdx.x;
  unsigned bt = 0;                    // barrier ordinal

  __shared__ int s_list[800];
  __shared__ int s_cnt;
  __shared__ int s_red[NTHR];
  __shared__ float stg[2][6144];      // [buf][tr | img | sppo], 32 b-rows x 64

  // ---- init: Wt[i][n] = Win[n][i], written coherently ----
  for (int e = blk * NTHR + tid; e < NOUT * INQ; e += GRID * NTHR) {
    int n = e / INQ, i = e % INQ;
    st_coh(Wt + (size_t)i * NP + n, Win[e]);
  }
  ++bt; gbar(bar, bt, blk);

  for (int t = 0; t < T_STEPS; ++t) {
    float* trC = (t & 1) ? trB : trA;   // pre_traces[t]
    float* trN = (t & 1) ? trA : trB;   // pre_traces[t+1]

    // ================= phase 1: block b = batch row =================
    {
      const int b = blk;
      const float* imrow = img + ((size_t)t * BATCH + b) * INQ;
      float* trCrow = trC + (size_t)b * INQ;
      float* trNrow = trN + (size_t)b * INQ;
      if (tid >= 64) {
        // waves 1-3: trace recurrence tr_{t+1} = 0.9*tr_t + img_t
        for (int i = tid - 64; i < INQ; i += NTHR - 64)
          st_coh(trNrow + i, fmaf(0.9f, ld_coh(trCrow + i), imrow[i]));
      } else {
        // wave 0: ordered active-index compaction, padded to multiple of 8
        int base = 0;
        for (int c = 0; c < INQ; c += 64) {
          int i = c + tid;
          bool act = (i < INQ) && (imrow[i] != 0.0f);
          unsigned long long m = __ballot(act);
          if (act) s_list[base + (int)__popcll(m & ((1ull << tid) - 1ull))] = i;
          base += (int)__popcll(m);
        }
        if (tid == 0) {
          int cr = (base + 7) & ~7;
          for (int j = base; j < cr; ++j) s_list[j] = 784;  // zero pad row
          s_cnt = cr;
        }
      }
      __syncthreads();
      const int cnt = s_cnt;            // multiple of 8
      const int anyPrev = (t > 0)
          ? (int)__hip_atomic_load(&flags[t - 1], __ATOMIC_RELAXED, __HIP_MEMORY_SCOPE_AGENT)
          : 0;
      const int wPrev = win[b];
      int localmin = 0x7fffffff;

      if (tid < 200) {
        const int n0 = tid * 2;
        const size_t sidx = (size_t)b * NP + n0;
        float2 sv = *(float2*)(syn + sidx);
        if (anyPrev) {
          if (n0     != wPrev) sv.x -= 0.1f;
          if (n0 + 1 != wPrev) sv.y -= 0.1f;
        }
        float c0 = 0.f, c1 = 0.f;
        for (int j = 0; j < cnt; j += 8) {   // 8 coherent loads in flight
          float2 w0 = ld_coh2(Wt + (size_t)s_list[j+0] * NP + n0);
          float2 w1 = ld_coh2(Wt + (size_t)s_list[j+1] * NP + n0);
          float2 w2 = ld_coh2(Wt + (size_t)s_list[j+2] * NP + n0);
          float2 w3 = ld_coh2(Wt + (size_t)s_list[j+3] * NP + n0);
          float2 w4 = ld_coh2(Wt + (size_t)s_list[j+4] * NP + n0);
          float2 w5 = ld_coh2(Wt + (size_t)s_list[j+5] * NP + n0);
          float2 w6 = ld_coh2(Wt + (size_t)s_list[j+6] * NP + n0);
          float2 w7 = ld_coh2(Wt + (size_t)s_list[j+7] * NP + n0);
          c0 += w0.x; c1 += w0.y;  c0 += w1.x; c1 += w1.y;
          c0 += w2.x; c1 += w2.y;  c0 += w3.x; c1 += w3.y;
          c0 += w4.x; c1 += w4.y;  c0 += w5.x; c1 += w5.y;
          c0 += w6.x; c1 += w6.y;  c0 += w7.x; c1 += w7.y;
        }
        float2 mv = *(float2*)(mem + sidx);
        float syn0 = fmaf(0.9f, sv.x, c0);
        float syn1 = fmaf(0.9f, sv.y, c1);
        float r0 = (mv.x > 1.0f) ? 1.0f : 0.0f;
        float r1 = (mv.y > 1.0f) ? 1.0f : 0.0f;
        float m0 = fmaf(0.8f, mv.x, syn0) - r0;
        float m1 = fmaf(0.8f, mv.y, syn1) - r1;
        float s0 = (m0 > 1.0f) ? 1.0f : 0.0f;
        float s1 = (m1 > 1.0f) ? 1.0f : 0.0f;
        *(float2*)(syn + sidx) = make_float2(syn0, syn1);
        *(float2*)(mem + sidx) = make_float2(m0, m1);
        // post trace; sppo is cross-XCD -> sc1 both ways
        float2 spA = ld_coh2(sppo + (size_t)b * 2 * NP + 2 * n0);
        float2 spB = ld_coh2(sppo + (size_t)b * 2 * NP + 2 * n0 + 2);
        float p0 = fmaf(0.9f, spA.y, s0);
        float p1 = fmaf(0.9f, spB.y, s1);
        st_coh2(sppo + (size_t)b * 2 * NP + 2 * n0,     make_float2(s0, p0));
        st_coh2(sppo + (size_t)b * 2 * NP + 2 * n0 + 2, make_float2(s1, p1));
        const size_t ridx = (size_t)t * BATCH * NOUT + (size_t)b * NOUT + n0;
        *(float2*)(mem_rec + ridx) = make_float2(m0, m1);
        *(float2*)(spk_rec + ridx) = make_float2(s0, s1);
        if      (s0 != 0.f) localmin = n0;
        else if (s1 != 0.f) localmin = n0 + 1;
      }
      s_red[tid] = localmin;
      __syncthreads();
      for (int o = NTHR / 2; o > 0; o >>= 1) {
        if (tid < o) s_red[tid] = min(s_red[tid], s_red[tid + o]);
        __syncthreads();
      }
      if (tid == 0) {
        int w = s_red[0];
        win[b] = (w == 0x7fffffff) ? 0 : w;
        if (w != 0x7fffffff)
          __hip_atomic_fetch_or(&flags[t], 1u, __ATOMIC_RELAXED, __HIP_MEMORY_SCOPE_AGENT);
      }
    }
    ++bt; gbar(bar, bt, blk);

    // ================= phase 2: STDP weight update (LDS-staged) =============
    if (blk < 169) {
      const int bi = blk / 13, bn = blk % 13;
      const int ib0 = bi * 64, nb0 = bn * 32;
      const int w = tid >> 6, l = tid & 63;
      const int brow0 = w * 4 + (l >> 4);
      int icol = ib0 + (l & 15) * 4;
      if (icol > INQ - 4) icol = INQ - 4;         // clamp (garbage, unused)
      const int scol = 2 * nb0 + (l & 15) * 4;
      const float* imgt = img + (size_t)t * BATCH * INQ;

      const int ib = ib0 + (tid >> 4) * 4;
      const int nb = nb0 + (tid & 15) * 2;
      const bool active = (ib < INQ) && (nb < NOUT);
      const int loff = (tid >> 4) * 4;
      const int soff = (tid & 15) * 4;

      float a00=0,a01=0,a10=0,a11=0,a20=0,a21=0,a30=0,a31=0;

      // stage chunk c (32 b-rows): tr/sppo coherent (sc1), img cached
      #define STG(c, buf) {                                                     \
        int b0_ = (c) * 32;                                                     \
        for (int q = 0; q < 2; ++q) {                                           \
          int br = b0_ + q * 16 + brow0;                                        \
          float* dst = &stg[buf][(q * 16 + w * 4) * 64];                        \
          gl_lds16c(trC  + (size_t)br * INQ  + icol, dst);                      \
          gl_lds16 (imgt + (size_t)br * INQ  + icol, dst + 2048);               \
          gl_lds16c(sppo + (size_t)br * 1024 + scol, dst + 4096);               \
        }                                                                       \
      }

      STG(0, 0);
      for (int c = 0; c < 8; ++c) {
        const int buf = c & 1;
        if (c < 7) {
          STG(c + 1, buf ^ 1);
          __builtin_amdgcn_s_waitcnt(0x0F76);     // vmcnt(6): chunk c landed
        } else {
          __builtin_amdgcn_s_waitcnt(0x0F70);     // vmcnt(0)
        }
        __builtin_amdgcn_s_barrier();
        if (active) {
          const float* Ltr = &stg[buf][loff];
          const float* Lim = &stg[buf][2048 + loff];
          const float* Lsp = &stg[buf][4096 + soff];
          #pragma unroll 4
          for (int bb = 0; bb < 32; ++bb) {       // b ascending: exact order
            float4 t4 = *(const float4*)(Ltr + bb * 64);
            float4 g4 = *(const float4*)(Lim + bb * 64);
            float4 sp = *(const float4*)(Lsp + bb * 64);
            float ap0 = 1e-3f * sp.x, am0 = 1e-3f * sp.y;
            float ap1 = 1e-3f * sp.z, am1 = 1e-3f * sp.w;
            a00 = fmaf(t4.x, ap0, fmaf(g4.x, -am0, a00));
            a01 = fmaf(t4.x, ap1, fmaf(g4.x, -am1, a01));
            a10 = fmaf(t4.y, ap0, fmaf(g4.y, -am0, a10));
            a11 = fmaf(t4.y, ap1, fmaf(g4.y, -am1, a11));
            a20 = fmaf(t4.z, ap0, fmaf(g4.z, -am0, a20));
            a21 = fmaf(t4.z, ap1, fmaf(g4.z, -am1, a21));
            a30 = fmaf(t4.w, ap0, fmaf(g4.w, -am0, a30));
            a31 = fmaf(t4.w, ap1, fmaf(g4.w, -am1, a31));
          }
        }
        __builtin_amdgcn_s_waitcnt(0xC07F);       // lgkmcnt(0) only
        __builtin_amdgcn_s_barrier();
      }
      #undef STG

      if (active) {
        float accs[4][2] = {{a00,a01},{a10,a11},{a20,a21},{a30,a31}};
        #pragma unroll
        for (int k = 0; k < 4; ++k) {
          float* wp = Wt + (size_t)(ib + k) * NP + nb;
          float2 w2 = ld_coh2(wp);                // coherent RMW of Wt
          w2.x = fminf(fmaxf(w2.x + accs[k][0], 0.f), 1.f);
          w2.y = fminf(fmaxf(w2.y + accs[k][1], 0.f), 1.f);
          st_coh2(wp, w2);
        }
      }
    }
    ++bt; gbar(bar, bt, blk);
  }

  // ---- final: W_out[n][i] = Wt[i][n] ----
  for (int e = blk * NTHR + tid; e < NOUT * INQ; e += GRID * NTHR) {
    int n = e / INQ, i = e % INQ;
    Wout[e] = ld_coh(Wt + (size_t)i * NP + n);
  }
}

extern "C" void kernel_launch(void* const* d_in, const int* in_sizes, int n_in,
                              void* d_out, int out_size, void* d_ws, size_t ws_size,
                              hipStream_t stream) {
  const float* img = (const float*)d_in[0];
  const float* W   = (const float*)d_in[1];
  float* out = (float*)d_out;
  float* ws  = (float*)d_ws;

  hipMemsetAsync(d_ws, 0, (size_t)WS_FLOATS * sizeof(float), stream);

  void* args[] = { (void*)&img, (void*)&W, (void*)&out, (void*)&ws };
  hipLaunchCooperativeKernel((const void*)snn_kernel, dim3(GRID), dim3(NTHR),
                             args, 0, stream);
}